// Round 12
// baseline (266.504 us; speedup 1.0000x reference)
//
#include <hip/hip_runtime.h>
#include <math.h>

// Problem constants (fixed shapes)
#define DIM    4096
#define NH     32
#define NKV    8
#define HD     128
#define BS     16
#define KVLEN  4096
#define LASTPOS 4095
#define QKV_COLS 6144   // 4096 q + 1024 k + 1024 v
#define NKC    64       // k-chunks for split-K projections

typedef float f32x4 __attribute__((ext_vector_type(4)));

// ws layout (floats):
//   qkv   : [16][6144]                @ 0        (98304)
//   attn  : [16][4096]                @ 98304    (65536)
//   part  : [2048 blocks][4][132]     @ 163840   (1081344)
//   pq    : [64][16][6144]            @ 1245184  (6291456)
//   pw    : [64][16][4096]            @ 7536640  (4194304)  end 11730944 (~47MB)
#define WS_QKV   0
#define WS_ATTN  98304
#define WS_PART  163840
#define WS_PQ    1245184
#define WS_PW    7536640

// ---------------------------------------------------------------------------
// K1a: qkv partials. block: 256 thr, 2 cols/thread (512 cols); grid (12, 64).
// ---------------------------------------------------------------------------
__global__ __launch_bounds__(256) void qkv_projA(
    const float* __restrict__ x, const float* __restrict__ wq,
    const float* __restrict__ wk, const float* __restrict__ wv,
    float* __restrict__ pq) {
  __shared__ float xs[16 * 64];
  const int tid = threadIdx.x;
  const int col = (blockIdx.x * 256 + tid) * 2;   // block-uniform matrix select
  const int kc = blockIdx.y;
  const int k0 = kc * 64;

  for (int i = tid; i < 1024; i += 256) {
    int b = i >> 6, k = i & 63;
    xs[i] = x[b * DIM + k0 + k];
  }
  __syncthreads();

  const float* w;
  int wstride, wcol;
  if (col < 4096)      { w = wq; wstride = 4096; wcol = col; }
  else if (col < 5120) { w = wk; wstride = 1024; wcol = col - 4096; }
  else                 { w = wv; wstride = 1024; wcol = col - 5120; }
  const float* wp = w + (size_t)k0 * wstride + wcol;

  float acc0[16], acc1[16];
#pragma unroll
  for (int b = 0; b < 16; ++b) { acc0[b] = 0.f; acc1[b] = 0.f; }

#pragma unroll 2
  for (int k = 0; k < 64; k += 4) {
    float2 w0 = *(const float2*)(wp + (size_t)(k + 0) * wstride);
    float2 w1 = *(const float2*)(wp + (size_t)(k + 1) * wstride);
    float2 w2 = *(const float2*)(wp + (size_t)(k + 2) * wstride);
    float2 w3 = *(const float2*)(wp + (size_t)(k + 3) * wstride);
#pragma unroll
    for (int b = 0; b < 16; ++b) {
      float4 xb = *(const float4*)(&xs[b * 64 + k]);
      acc0[b] += xb.x * w0.x + xb.y * w1.x + xb.z * w2.x + xb.w * w3.x;
      acc1[b] += xb.x * w0.y + xb.y * w1.y + xb.z * w2.y + xb.w * w3.y;
    }
  }
#pragma unroll
  for (int b = 0; b < 16; ++b) {
    *(float2*)(&pq[((size_t)kc * 16 + b) * QKV_COLS + col]) = make_float2(acc0[b], acc1[b]);
  }
}

// ---------------------------------------------------------------------------
// K1b: reduce 64 qkv partials + fused RoPE (+ q scale).
// ---------------------------------------------------------------------------
__global__ __launch_bounds__(256) void qkv_projB(
    const float* __restrict__ pq, float* __restrict__ qkv,
    const float* __restrict__ fc, const float* __restrict__ fs) {
  int t = blockIdx.x * 256 + threadIdx.x;       // 0..49151
  int b = t / 3072, pr = t % 3072;
  int col = 2 * pr;
  float e = 0.f, o = 0.f;
#pragma unroll 8
  for (int kc = 0; kc < NKC; ++kc) {
    float2 v = *(const float2*)(&pq[((size_t)kc * 16 + b) * QKV_COLS + col]);
    e += v.x; o += v.y;
  }
  float re = e, im = o;
  if (col < 5120) {  // q or k: rope
    int i = (col & 127) >> 1;
    float c = fc[i], s = fs[i];
    float scale = (col < 4096) ? 0.08838834764831845f : 1.0f;
    re = (e * c - o * s) * scale;
    im = (e * s + o * c) * scale;
  }
  *(float2*)(&qkv[b * QKV_COLS + col]) = make_float2(re, im);
}

// ---------------------------------------------------------------------------
// K3: attention — register double-buffered pipeline (never drains vmcnt to 0
// mid-loop), zero LDS in the hot loop, one final barrier for block combine.
// Block = (bg, 256-row chunk), 256 thr = 4 waves; wave owns 64 rows.
// Lane map: 64 lanes = 2 rows (p2) x 32 d-quads (ql). Per 8-row batch:
// issue NEXT batch's 8 loads -> compute current (16 dots, butterfly, online
// softmax, PV with no shuffles). Fully unrolled so kf[buf] indices static.
// ---------------------------------------------------------------------------
__global__ __launch_bounds__(256) void attn_partial(
    const float* __restrict__ cache_k, const float* __restrict__ cache_v,
    const float* __restrict__ qkv, float* __restrict__ part) {
  __shared__ float red[4][4][130];
  const int tid = threadIdx.x;
  const int w = tid >> 6, lane = tid & 63;
  const int p2 = lane >> 5, ql = lane & 31;
  const int chunk = blockIdx.x & 15;
  const int bg = blockIdx.x >> 4;
  const int b = bg >> 3, g = bg & 7;
  const int t0 = chunk * 256 + w * 64;          // wave's first kv row

  // q regs: head h, d=[ql*4,+4)
  const float* qbase = qkv + b * QKV_COLS + g * 512;
  f32x4 qh[4];
#pragma unroll
  for (int h = 0; h < 4; ++h) qh[h] = *(const f32x4*)(qbase + h * 128 + ql * 4);

  const float* kw = cache_k + (size_t)b * 4194304 + g * 128 + (size_t)t0 * 1024;
  const float* vw = cache_v + (size_t)b * 4194304 + g * 128 + (size_t)t0 * 1024;
  const float* xk = qkv + b * QKV_COLS + 4096 + g * 128;
  const float* xv = qkv + b * QKV_COLS + 5120 + g * 128;

  float m[4], l[4];
  f32x4 acc[4];
#pragma unroll
  for (int h = 0; h < 4; ++h) { m[h] = -1e30f; l[h] = 0.f; acc[h] = (f32x4)(0.f); }

  const bool haslast = (t0 + 63 == LASTPOS);    // chunk 15, wave 3 only

  f32x4 kf[2][4], vf[2][4];

#define LOADKV(buf, bt)                                                      \
  {                                                                          \
    const float* kb8 = kw + (bt) * 8192;                                     \
    const float* vb8 = vw + (bt) * 8192;                                     \
    if (!haslast || (bt) < 7) {                                              \
      _Pragma("unroll")                                                      \
      for (int j = 0; j < 4; ++j)                                            \
        kf[buf][j] = *(const f32x4*)(kb8 + (2 * j + p2) * 1024 + ql * 4);    \
      _Pragma("unroll")                                                      \
      for (int j = 0; j < 4; ++j)                                            \
        vf[buf][j] = *(const f32x4*)(vb8 + (2 * j + p2) * 1024 + ql * 4);    \
    } else {                                                                 \
      _Pragma("unroll")                                                      \
      for (int j = 0; j < 4; ++j) {                                          \
        int t = t0 + 56 + 2 * j + p2;                                        \
        const float* kr = (t == LASTPOS) ? xk : (kb8 + (2 * j + p2) * 1024); \
        kf[buf][j] = *(const f32x4*)(kr + ql * 4);                           \
        const float* vr = (t == LASTPOS) ? xv : (vb8 + (2 * j + p2) * 1024); \
        vf[buf][j] = *(const f32x4*)(vr + ql * 4);                           \
      }                                                                      \
    }                                                                        \
  }

  LOADKV(0, 0);   // prologue

#pragma unroll
  for (int bt = 0; bt < 8; ++bt) {
    const int cur = bt & 1;
    if (bt < 7) { LOADKV(cur ^ 1, bt + 1); }   // next batch in flight

    // 16 dots on current batch
    float sv[4][4];
#pragma unroll
    for (int j = 0; j < 4; ++j) {
#pragma unroll
      for (int h = 0; h < 4; ++h) {
        f32x4 pr = kf[cur][j] * qh[h];
        sv[j][h] = pr[0] + pr[1] + pr[2] + pr[3];
      }
    }
    // butterfly reduce across the 32 d-lanes
#pragma unroll
    for (int off = 1; off < 32; off <<= 1) {
#pragma unroll
      for (int j = 0; j < 4; ++j) {
#pragma unroll
        for (int h = 0; h < 4; ++h)
          sv[j][h] += __shfl_xor(sv[j][h], off);
      }
    }

    // online softmax update per head
#pragma unroll
    for (int h = 0; h < 4; ++h) {
      float bm = fmaxf(fmaxf(sv[0][h], sv[1][h]), fmaxf(sv[2][h], sv[3][h]));
      bm = fmaxf(bm, __shfl_xor(bm, 32));      // combine parity halves
      float mn = fmaxf(m[h], bm);
      float f = __expf(m[h] - mn);
      m[h] = mn;
      acc[h] *= f;
#pragma unroll
      for (int j = 0; j < 4; ++j) sv[j][h] = __expf(sv[j][h] - mn);
      float ls = sv[0][h] + sv[1][h] + sv[2][h] + sv[3][h];
      ls += __shfl_xor(ls, 32);
      l[h] = l[h] * f + ls;
    }

    // PV (no shuffles: lane owns its row's probs)
#pragma unroll
    for (int j = 0; j < 4; ++j) {
#pragma unroll
      for (int h = 0; h < 4; ++h) acc[h] += sv[j][h] * vf[cur][j];
    }
  }
#undef LOADKV

  // combine parity halves of acc
#pragma unroll
  for (int h = 0; h < 4; ++h) {
#pragma unroll
    for (int k = 0; k < 4; ++k) acc[h][k] += __shfl_xor(acc[h][k], 32);
  }

  // wave partial -> LDS
  if (lane < 32) {
#pragma unroll
    for (int h = 0; h < 4; ++h)
      *(f32x4*)(&red[w][h][ql * 4]) = acc[h];
  }
  if (lane == 0) {
#pragma unroll
    for (int h = 0; h < 4; ++h) {
      red[w][h][128] = m[h];
      red[w][h][129] = l[h];
    }
  }
  __syncthreads();

  // block combine: 4 waves' (m,l,o) -> one partial per head
  for (int item = tid; item < 512; item += 256) {
    int h = item >> 7, d = item & 127;
    float M = -1e30f;
#pragma unroll
    for (int w2 = 0; w2 < 4; ++w2) M = fmaxf(M, red[w2][h][128]);
    float num = 0.f, den = 0.f;
#pragma unroll
    for (int w2 = 0; w2 < 4; ++w2) {
      float wgt = __expf(red[w2][h][128] - M);
      num += wgt * red[w2][h][d];
      den += wgt * red[w2][h][129];
    }
    size_t pi = ((size_t)blockIdx.x * 4 + h) * 132;
    part[pi + d] = num;
    if (d == 0) { part[pi + 128] = M; part[pi + 129] = den; }
  }
}

// ---------------------------------------------------------------------------
// K4: online-merge 16 chunk-partials per (bg,h,d) -> attn_out. 65536 thr.
// ---------------------------------------------------------------------------
__global__ __launch_bounds__(256) void attn_combine(
    const float* __restrict__ part, float* __restrict__ attn_out) {
  int t = blockIdx.x * 256 + threadIdx.x;   // 0..65535
  int d = t & 127, h = (t >> 7) & 3, bg = t >> 9;
  int b = bg >> 3, g = bg & 7;
  float M = -1e30f, num = 0.f, den = 0.f;
#pragma unroll 4
  for (int c = 0; c < 16; ++c) {
    const float* pr = part + ((size_t)(bg * 16 + c) * 4 + h) * 132;
    float mc = pr[128];
    float Mn = fmaxf(M, mc);
    float fo = __expf(M - Mn);
    float fcur = __expf(mc - Mn);
    num = num * fo + fcur * pr[d];
    den = den * fo + fcur * pr[129];
    M = Mn;
  }
  attn_out[b * DIM + (g * 4 + h) * 128 + d] = num / den;
}

// ---------------------------------------------------------------------------
// K5a: wo partials. block: 256 thr, 2 cols/thread (512 cols); grid (8, 64).
// ---------------------------------------------------------------------------
__global__ __launch_bounds__(256) void out_projA(
    const float* __restrict__ attn, const float* __restrict__ wo,
    float* __restrict__ pw) {
  __shared__ float xs[16 * 64];
  const int tid = threadIdx.x;
  const int col = (blockIdx.x * 256 + tid) * 2;  // 0..4094
  const int kc = blockIdx.y;
  const int k0 = kc * 64;

  for (int i = tid; i < 1024; i += 256) {
    int b = i >> 6, k = i & 63;
    xs[i] = attn[b * DIM + k0 + k];
  }
  __syncthreads();

  const float* wp = wo + (size_t)k0 * 4096 + col;
  float acc0[16], acc1[16];
#pragma unroll
  for (int b = 0; b < 16; ++b) { acc0[b] = 0.f; acc1[b] = 0.f; }

#pragma unroll 2
  for (int k = 0; k < 64; k += 4) {
    float2 w0 = *(const float2*)(wp + (size_t)(k + 0) * 4096);
    float2 w1 = *(const float2*)(wp + (size_t)(k + 1) * 4096);
    float2 w2 = *(const float2*)(wp + (size_t)(k + 2) * 4096);
    float2 w3 = *(const float2*)(wp + (size_t)(k + 3) * 4096);
#pragma unroll
    for (int b = 0; b < 16; ++b) {
      float4 xb = *(const float4*)(&xs[b * 64 + k]);
      acc0[b] += xb.x * w0.x + xb.y * w1.x + xb.z * w2.x + xb.w * w3.x;
      acc1[b] += xb.x * w0.y + xb.y * w1.y + xb.z * w2.y + xb.w * w3.y;
    }
  }
#pragma unroll
  for (int b = 0; b < 16; ++b) {
    *(float2*)(&pw[((size_t)kc * 16 + b) * DIM + col]) = make_float2(acc0[b], acc1[b]);
  }
}

// ---------------------------------------------------------------------------
// K5b: reduce 64 wo partials -> d_out.
// ---------------------------------------------------------------------------
__global__ __launch_bounds__(256) void out_projB(
    const float* __restrict__ pw, float* __restrict__ out) {
  int t = blockIdx.x * 256 + threadIdx.x;  // 65536
  int b = t >> 12, col = t & 4095;
  float sum = 0.f;
#pragma unroll 8
  for (int kc = 0; kc < NKC; ++kc)
    sum += pw[((size_t)kc * 16 + b) * DIM + col];
  out[b * DIM + col] = sum;
}

// ---------------------------------------------------------------------------
extern "C" void kernel_launch(void* const* d_in, const int* in_sizes, int n_in,
                              void* d_out, int out_size, void* d_ws, size_t ws_size,
                              hipStream_t stream) {
  const float* x  = (const float*)d_in[0];
  const float* wq = (const float*)d_in[1];
  const float* wk = (const float*)d_in[2];
  const float* wv = (const float*)d_in[3];
  const float* wo = (const float*)d_in[4];
  const float* ck = (const float*)d_in[5];
  const float* cv = (const float*)d_in[6];
  const float* fc = (const float*)d_in[7];
  const float* fs = (const float*)d_in[8];

  float* ws_f  = (float*)d_ws;
  float* qkv   = ws_f + WS_QKV;
  float* attn  = ws_f + WS_ATTN;
  float* part  = ws_f + WS_PART;
  float* pq    = ws_f + WS_PQ;
  float* pw    = ws_f + WS_PW;
  float* out   = (float*)d_out;

  qkv_projA<<<dim3(12, NKC), 256, 0, stream>>>(x, wq, wk, wv, pq);
  qkv_projB<<<192, 256, 0, stream>>>(pq, qkv, fc, fs);
  attn_partial<<<2048, 256, 0, stream>>>(ck, cv, qkv, part);
  attn_combine<<<256, 256, 0, stream>>>(part, attn);
  out_projA<<<dim3(8, NKC), 256, 0, stream>>>(attn, wo, pw);
  out_projB<<<256, 256, 0, stream>>>(pw, out);
}

// Round 13
// 195.895 us; speedup vs baseline: 1.3604x; 1.3604x over previous
//
#include <hip/hip_runtime.h>
#include <math.h>

// Problem constants (fixed shapes)
#define DIM    4096
#define NH     32
#define NKV    8
#define HD     128
#define BS     16
#define KVLEN  4096
#define LASTPOS 4095
#define QKV_COLS 6144   // 4096 q + 1024 k + 1024 v
#define CHUNK  512      // kv rows per attn block
#define NCH    8        // number of kv chunks
#define SS_STR 520      // padded score-row stride (520%32==8 -> conflict-free)
#define NKC    64       // k-chunks for split-K projections

// ws layout (floats):
//   qkv       : [16][6144]               @ 0         (98304)
//   attn_out  : [16][4096]               @ 98304     (65536)
//   part      : [128][8][4][130]         @ 163840    (532480)
//   pq (qkvA) : [64][16][6144]           @ 2326528   (6291456)
//   pw (woA)  : [64][16][4096]           @ 8617984   (4194304)  end 12812288 (~51MB)
#define WS_QKV   0
#define WS_ATTN  98304
#define WS_PART  163840
#define WS_PQ    2326528
#define WS_PW    8617984

// ---------------------------------------------------------------------------
// K1a: qkv partials. block: 256 thr, 2 cols/thread (512 cols); grid (12, 64).
// ---------------------------------------------------------------------------
__global__ __launch_bounds__(256) void qkv_projA(
    const float* __restrict__ x, const float* __restrict__ wq,
    const float* __restrict__ wk, const float* __restrict__ wv,
    float* __restrict__ pq) {
  __shared__ float xs[16 * 64];
  const int tid = threadIdx.x;
  const int col = (blockIdx.x * 256 + tid) * 2;   // block-uniform matrix select
  const int kc = blockIdx.y;
  const int k0 = kc * 64;

  for (int i = tid; i < 1024; i += 256) {
    int b = i >> 6, k = i & 63;
    xs[i] = x[b * DIM + k0 + k];
  }
  __syncthreads();

  const float* w;
  int wstride, wcol;
  if (col < 4096)      { w = wq; wstride = 4096; wcol = col; }
  else if (col < 5120) { w = wk; wstride = 1024; wcol = col - 4096; }
  else                 { w = wv; wstride = 1024; wcol = col - 5120; }
  const float* wp = w + (size_t)k0 * wstride + wcol;

  float acc0[16], acc1[16];
#pragma unroll
  for (int b = 0; b < 16; ++b) { acc0[b] = 0.f; acc1[b] = 0.f; }

#pragma unroll 2
  for (int k = 0; k < 64; k += 4) {
    float2 w0 = *(const float2*)(wp + (size_t)(k + 0) * wstride);
    float2 w1 = *(const float2*)(wp + (size_t)(k + 1) * wstride);
    float2 w2 = *(const float2*)(wp + (size_t)(k + 2) * wstride);
    float2 w3 = *(const float2*)(wp + (size_t)(k + 3) * wstride);
#pragma unroll
    for (int b = 0; b < 16; ++b) {
      float4 xb = *(const float4*)(&xs[b * 64 + k]);
      acc0[b] += xb.x * w0.x + xb.y * w1.x + xb.z * w2.x + xb.w * w3.x;
      acc1[b] += xb.x * w0.y + xb.y * w1.y + xb.z * w2.y + xb.w * w3.y;
    }
  }
#pragma unroll
  for (int b = 0; b < 16; ++b) {
    *(float2*)(&pq[((size_t)kc * 16 + b) * QKV_COLS + col]) = make_float2(acc0[b], acc1[b]);
  }
}

// ---------------------------------------------------------------------------
// K1b: reduce 64 qkv partials + fused RoPE (+ q scale).
// ---------------------------------------------------------------------------
__global__ __launch_bounds__(256) void qkv_projB(
    const float* __restrict__ pq, float* __restrict__ qkv,
    const float* __restrict__ fc, const float* __restrict__ fs) {
  int t = blockIdx.x * 256 + threadIdx.x;       // 0..49151
  int b = t / 3072, pr = t % 3072;
  int col = 2 * pr;
  float e = 0.f, o = 0.f;
#pragma unroll 8
  for (int kc = 0; kc < NKC; ++kc) {
    float2 v = *(const float2*)(&pq[((size_t)kc * 16 + b) * QKV_COLS + col]);
    e += v.x; o += v.y;
  }
  float re = e, im = o;
  if (col < 5120) {  // q or k: rope
    int i = (col & 127) >> 1;
    float c = fc[i], s = fs[i];
    float scale = (col < 4096) ? 0.08838834764831845f : 1.0f;
    re = (e * c - o * s) * scale;
    im = (e * s + o * c) * scale;
  }
  *(float2*)(&qkv[b * QKV_COLS + col]) = make_float2(re, im);
}

// ---------------------------------------------------------------------------
// K3: attention partials. block = (b, g, chunk of 512 kv rows), 512 thr =
// 8 waves (R5 structure, chunk doubled: halves per-block fixed costs while
// grid 1024 = exactly 4 blocks/CU keeps 32 waves/CU nominal occupancy).
// Scores: 16-lane groups own a K row (4 rows/wave/iter), lane holds 8 d,
//         4-deep shfl_xor reduce. Wave w covers rows [w*64, w*64+64).
// Softmax: waves 0-3, head = wave id (chunk-local partial).
// PV: wave w covers rows [w*64, w*64+64) for ALL 4 heads; half-wave owns a
//     row, lane loads float4, unroll 8; shfl_xor(32) + LDS cross-wave combine.
// ---------------------------------------------------------------------------
__global__ __launch_bounds__(512, 4) void attn_partial(
    const float* __restrict__ cache_k, const float* __restrict__ cache_v,
    const float* __restrict__ qkv, float* __restrict__ part) {
  __shared__ float qs[512];
  __shared__ float ss[4 * SS_STR];
  __shared__ float pacc[8][4][128];
  const int tid = threadIdx.x;
  const int w = tid >> 6, lane = tid & 63;
  const int p = lane >> 4, ql = lane & 15;
  const int chunk = blockIdx.x & (NCH - 1);
  const int bg = blockIdx.x >> 3;
  const int b = bg >> 3, g = bg & 7;

  qs[tid] = qkv[b * QKV_COLS + g * 512 + tid];
  __syncthreads();

  // Q fragments: head h, d-range [ql*8, ql*8+8)
  float4 qA[4], qB[4];
#pragma unroll
  for (int h = 0; h < 4; ++h) {
    qA[h] = *(const float4*)(&qs[h * 128 + ql * 8]);
    qB[h] = *(const float4*)(&qs[h * 128 + ql * 8 + 4]);
  }

  const int t0 = chunk * CHUNK;
  const float* kbase = cache_k + ((size_t)b * 4096 * 8 + g) * 128;
  const float* xk    = qkv + b * QKV_COLS + 4096 + g * 128;

  // ---- scores ----
#pragma unroll 2
  for (int it = 0; it < 16; ++it) {
    int r = w * 64 + it * 4 + p;
    int t = t0 + r;
    const float* krow = (t == LASTPOS) ? xk : (kbase + (size_t)t * 1024);
    float4 k0 = *(const float4*)(krow + ql * 8);
    float4 k1 = *(const float4*)(krow + ql * 8 + 4);
    float s[4];
#pragma unroll
    for (int h = 0; h < 4; ++h) {
      s[h] = k0.x * qA[h].x + k0.y * qA[h].y + k0.z * qA[h].z + k0.w * qA[h].w
           + k1.x * qB[h].x + k1.y * qB[h].y + k1.z * qB[h].z + k1.w * qB[h].w;
    }
#pragma unroll
    for (int off = 1; off < 16; off <<= 1) {
#pragma unroll
      for (int h = 0; h < 4; ++h) s[h] += __shfl_xor(s[h], off);
    }
    float v = (ql == 0) ? s[0] : (ql == 1) ? s[1] : (ql == 2) ? s[2] : s[3];
    if (ql < 4) ss[ql * SS_STR + r] = v;
  }
  __syncthreads();

  // ---- chunk-local softmax, head = wave (waves 0-3) ----
  float* prow = part + ((size_t)(bg * NCH + chunk) * 4 + (w & 3)) * 130;
  if (w < 4) {
    float vals[8];
    float m = -1e30f;
#pragma unroll
    for (int i = 0; i < 8; ++i) {
      vals[i] = ss[w * SS_STR + lane + 64 * i];
      m = fmaxf(m, vals[i]);
    }
#pragma unroll
    for (int off = 1; off < 64; off <<= 1) m = fmaxf(m, __shfl_xor(m, off));
    float l = 0.f;
#pragma unroll
    for (int i = 0; i < 8; ++i) {
      float pe = __expf(vals[i] - m);
      ss[w * SS_STR + lane + 64 * i] = pe;
      l += pe;
    }
#pragma unroll
    for (int off = 1; off < 64; off <<= 1) l += __shfl_xor(l, off);
    if (lane == 0) { prow[128] = m; prow[129] = l; }
  }
  __syncthreads();

  // ---- PV: wave w covers rows [w*64, w*64+64), half-wave owns a row ----
  const float* vbase = cache_v + ((size_t)b * 4096 * 8 + g) * 128;
  const float* xv    = qkv + b * QKV_COLS + 5120 + g * 128;
  const int h2 = lane >> 5;
  const int dq = lane & 31;
  float4 acc[4];
#pragma unroll
  for (int h = 0; h < 4; ++h) acc[h] = make_float4(0.f, 0.f, 0.f, 0.f);

#pragma unroll 8
  for (int j = 0; j < 32; ++j) {
    int r = w * 64 + 2 * j + h2;
    int t = t0 + r;
    const float* vrow = (t == LASTPOS) ? xv : (vbase + (size_t)t * 1024);
    float4 vv = *(const float4*)(vrow + dq * 4);
    float p0 = ss[0 * SS_STR + r];
    float p1 = ss[1 * SS_STR + r];
    float p2 = ss[2 * SS_STR + r];
    float p3 = ss[3 * SS_STR + r];
    acc[0].x += p0 * vv.x; acc[0].y += p0 * vv.y; acc[0].z += p0 * vv.z; acc[0].w += p0 * vv.w;
    acc[1].x += p1 * vv.x; acc[1].y += p1 * vv.y; acc[1].z += p1 * vv.z; acc[1].w += p1 * vv.w;
    acc[2].x += p2 * vv.x; acc[2].y += p2 * vv.y; acc[2].z += p2 * vv.z; acc[2].w += p2 * vv.w;
    acc[3].x += p3 * vv.x; acc[3].y += p3 * vv.y; acc[3].z += p3 * vv.z; acc[3].w += p3 * vv.w;
  }
#pragma unroll
  for (int h = 0; h < 4; ++h) {
    acc[h].x += __shfl_xor(acc[h].x, 32);
    acc[h].y += __shfl_xor(acc[h].y, 32);
    acc[h].z += __shfl_xor(acc[h].z, 32);
    acc[h].w += __shfl_xor(acc[h].w, 32);
  }
  if (lane < 32) {
#pragma unroll
    for (int h = 0; h < 4; ++h)
      *(float4*)(&pacc[w][h][dq * 4]) = acc[h];
  }
  __syncthreads();

  // ---- cross-wave combine: 512 threads = 4 heads x 128 d ----
  {
    int h = tid >> 7, d = tid & 127;
    float sum = 0.f;
#pragma unroll
    for (int w2 = 0; w2 < 8; ++w2) sum += pacc[w2][h][d];
    part[((size_t)(bg * NCH + chunk) * 4 + h) * 130 + d] = sum;
  }
}

// ---------------------------------------------------------------------------
// K4: combine 8 chunk-partials per (b,g,r,d) -> attn_out[b][h][d]
// ---------------------------------------------------------------------------
__global__ __launch_bounds__(256) void attn_combine(
    const float* __restrict__ part, float* __restrict__ attn_out) {
  int t = blockIdx.x * 256 + threadIdx.x;  // 65536
  int d = t & 127, r = (t >> 7) & 3, bg = t >> 9;
  int b = bg >> 3, g = bg & 7;
  float M = -1e30f;
  float ms[NCH];
#pragma unroll
  for (int c = 0; c < NCH; ++c) {
    ms[c] = part[((size_t)(bg * NCH + c) * 4 + r) * 130 + 128];
    M = fmaxf(M, ms[c]);
  }
  float num = 0.f, den = 0.f;
#pragma unroll
  for (int c = 0; c < NCH; ++c) {
    const float* prow = part + ((size_t)(bg * NCH + c) * 4 + r) * 130;
    float wgt = __expf(ms[c] - M);
    num += wgt * prow[d];
    den += wgt * prow[129];
  }
  attn_out[b * DIM + (g * 4 + r) * 128 + d] = num / den;
}

// ---------------------------------------------------------------------------
// K5a: wo partials. block: 256 thr, 2 cols/thread (512 cols); grid (8, 64).
// ---------------------------------------------------------------------------
__global__ __launch_bounds__(256) void out_projA(
    const float* __restrict__ attn, const float* __restrict__ wo,
    float* __restrict__ pw) {
  __shared__ float xs[16 * 64];
  const int tid = threadIdx.x;
  const int col = (blockIdx.x * 256 + tid) * 2;  // 0..4094
  const int kc = blockIdx.y;
  const int k0 = kc * 64;

  for (int i = tid; i < 1024; i += 256) {
    int b = i >> 6, k = i & 63;
    xs[i] = attn[b * DIM + k0 + k];
  }
  __syncthreads();

  const float* wp = wo + (size_t)k0 * 4096 + col;
  float acc0[16], acc1[16];
#pragma unroll
  for (int b = 0; b < 16; ++b) { acc0[b] = 0.f; acc1[b] = 0.f; }

#pragma unroll 2
  for (int k = 0; k < 64; k += 4) {
    float2 w0 = *(const float2*)(wp + (size_t)(k + 0) * 4096);
    float2 w1 = *(const float2*)(wp + (size_t)(k + 1) * 4096);
    float2 w2 = *(const float2*)(wp + (size_t)(k + 2) * 4096);
    float2 w3 = *(const float2*)(wp + (size_t)(k + 3) * 4096);
#pragma unroll
    for (int b = 0; b < 16; ++b) {
      float4 xb = *(const float4*)(&xs[b * 64 + k]);
      acc0[b] += xb.x * w0.x + xb.y * w1.x + xb.z * w2.x + xb.w * w3.x;
      acc1[b] += xb.x * w0.y + xb.y * w1.y + xb.z * w2.y + xb.w * w3.y;
    }
  }
#pragma unroll
  for (int b = 0; b < 16; ++b) {
    *(float2*)(&pw[((size_t)kc * 16 + b) * DIM + col]) = make_float2(acc0[b], acc1[b]);
  }
}

// ---------------------------------------------------------------------------
// K5b: reduce 64 wo partials -> d_out.
// ---------------------------------------------------------------------------
__global__ __launch_bounds__(256) void out_projB(
    const float* __restrict__ pw, float* __restrict__ out) {
  int t = blockIdx.x * 256 + threadIdx.x;  // 65536
  int b = t >> 12, col = t & 4095;
  float sum = 0.f;
#pragma unroll 8
  for (int kc = 0; kc < NKC; ++kc)
    sum += pw[((size_t)kc * 16 + b) * DIM + col];
  out[b * DIM + col] = sum;
}

// ---------------------------------------------------------------------------
extern "C" void kernel_launch(void* const* d_in, const int* in_sizes, int n_in,
                              void* d_out, int out_size, void* d_ws, size_t ws_size,
                              hipStream_t stream) {
  const float* x  = (const float*)d_in[0];
  const float* wq = (const float*)d_in[1];
  const float* wk = (const float*)d_in[2];
  const float* wv = (const float*)d_in[3];
  const float* wo = (const float*)d_in[4];
  const float* ck = (const float*)d_in[5];
  const float* cv = (const float*)d_in[6];
  const float* fc = (const float*)d_in[7];
  const float* fs = (const float*)d_in[8];

  float* ws_f  = (float*)d_ws;
  float* qkv   = ws_f + WS_QKV;
  float* attn  = ws_f + WS_ATTN;
  float* part  = ws_f + WS_PART;
  float* pq    = ws_f + WS_PQ;
  float* pw    = ws_f + WS_PW;
  float* out   = (float*)d_out;

  qkv_projA<<<dim3(12, NKC), 256, 0, stream>>>(x, wq, wk, wv, pq);
  qkv_projB<<<192, 256, 0, stream>>>(pq, qkv, fc, fs);
  attn_partial<<<128 * NCH, 512, 0, stream>>>(ck, cv, qkv, part);
  attn_combine<<<256, 256, 0, stream>>>(part, attn);
  out_projA<<<dim3(8, NKC), 256, 0, stream>>>(attn, wo, pw);
  out_projB<<<256, 256, 0, stream>>>(pw, out);
}